// Round 1
// baseline (173.518 us; speedup 1.0000x reference)
//
#include <hip/hip_runtime.h>

// SpaNn belief-propagation decoder, sparse reformulation (round 3).
// N=1024 vars x DV=4 edges = E=4096; M=512 checks x DC=8.
// var_of_edge[e] = e>>2 (static). Check connectivity recovered from
// w_odd_to_even via each row's leftmost nonzero column f[e]:
// for a check with edges e1<e2<...<e8, f(e1)=e2 and f(ek>=2)=e1, so
//   key(e) = (f(f(e))==e && e<f(e)) ? e : f(e)
// maps every edge to its check's minimum edge.
//
// Round-3 changes (all FP op sequences bitwise-identical to round 2):
//  - k1: 3-deep software-pipelined chunk scan (kills dependent load chain)
//  - solve: ballot/popcount slot assignment (no serial same-address atomic)
//  - solve: Batcher 19-CE sorting network on named registers (the insertion
//    sort's runtime-indexed v[8] was spilling to scratch — rule #20)
//  - solve: even phase split 2 threads/check, branchless half-select ->
//    4 atanhf/thread on all 16 waves instead of 8 on 8 waves
//  - solve: exact prefix-continue leave-one-out products (35 muls, same
//    left-to-right multiply order as np.prod)
//  - int4/float4 vectorized global+LDS access; ce[] lists hoisted out of
//    the BP iteration loop

#define En 4096
#define Nn 1024
#define Mn 512
#define EPSF 1.1920929e-07f

// ---------------------------------------------------------------------------
// Kernel 1: per row, find leftmost nonzero column. One wave per row,
// 1 KB chunks, ballot exit, 3 chunks in flight. Every row has 7 nonzeros,
// so the leftmost is at column <= 4089 and the loop always terminates.
// ---------------------------------------------------------------------------
__global__ __launch_bounds__(256) void find_first_peer(
    const float* __restrict__ w, int* __restrict__ f) {
  const int lane = threadIdx.x & 63;
  const int wv   = threadIdx.x >> 6;
  const int row  = blockIdx.x * 4 + wv;
  const float4* rowp = (const float4*)(w + (size_t)row * En);

  // invariant at loop head: v0=chunk(base), v1=chunk(base+256), v2=chunk(base+512)
  float4 v0 = rowp[lane];
  float4 v1 = rowp[64 + lane];
  float4 v2 = rowp[128 + lane];
  for (int base = 0;; base += 256) {
    bool any = (v0.x != 0.0f) | (v0.y != 0.0f) | (v0.z != 0.0f) | (v0.w != 0.0f);
    unsigned long long m = __ballot(any);
    if (m) {
      if (lane == __ffsll(m) - 1) {
        int off = (v0.x != 0.0f) ? 0 : (v0.y != 0.0f) ? 1 : (v0.z != 0.0f) ? 2 : 3;
        f[row] = base + 4 * lane + off;
      }
      break;
    }
    v0 = v1;
    v1 = v2;
    int nxt = base + 768;                 // floats; next chunk to prefetch
    if (nxt > En - 256) nxt = En - 256;   // clamp: redundant refetch, never OOB
    v2 = rowp[(nxt >> 2) + lane];
  }
}

// ---------------------------------------------------------------------------
// Kernel 2: rebuild check lists from f[] in LDS, then 5 BP iterations +
// output. Single workgroup, 1024 threads; thread t = variable t (edges
// 4t..4t+3); thread pair (2c, 2c+1) owns check c in the even phase.
// ---------------------------------------------------------------------------
__global__ __launch_bounds__(1024) void solve(
    const float* __restrict__ x, const int* __restrict__ f_g,
    float* __restrict__ out) {
  __shared__ int   fs[En];       // 16 KB  leftmost-peer
  __shared__ int   slotmap[En];  // 16 KB  min-edge -> check slot
  __shared__ int   ce[En];       // 16 KB  check -> 8 edges (ascending)
  __shared__ float ods[En];      // 16 KB  tanh(odd) messages
  __shared__ float evs[En];      // 16 KB  even messages
  __shared__ int   cnt[Mn];      //  2 KB  fill position per check
  __shared__ int   wtot[16];     //        min-edge count per wave
  const int t    = threadIdx.x;
  const int lane = t & 63;
  const int wv   = t >> 6;

  // ---- preamble: load f, derive keys, assign check slots (ballot scan) ----
  int4 fv = ((const int4*)f_g)[t];
  *((int4*)&fs[4 * t]) = fv;
  if (t < Mn) cnt[t] = 0;
  __syncthreads();

  const int fearr[4] = {fv.x, fv.y, fv.z, fv.w};
  int  keys[4];
  bool ismin[4];
#pragma unroll
  for (int k = 0; k < 4; ++k) {
    int e   = 4 * t + k;
    int fe  = fearr[k];
    int ffe = fs[fe];
    keys[k]  = (ffe == e && e < fe) ? e : fe;  // check's minimum edge
    ismin[k] = (keys[k] == e);
  }
  // unique slot per min-edge: wave-local rank via ballot+popcount, then
  // per-wave base via a tiny LDS scan. Slot ordering is arbitrary.
  const unsigned long long ltmask = (1ull << lane) - 1ull;
  int pre = 0;
  int rank[4];
#pragma unroll
  for (int k = 0; k < 4; ++k) {
    unsigned long long b = __ballot(ismin[k]);
    rank[k] = pre + (int)__popcll(b & ltmask);
    pre    += (int)__popcll(b);
  }
  if (lane == 0) wtot[wv] = pre;
  __syncthreads();
  int wbase = 0;
  for (int w = 0; w < wv; ++w) wbase += wtot[w];  // broadcast LDS reads
#pragma unroll
  for (int k = 0; k < 4; ++k)
    if (ismin[k]) slotmap[4 * t + k] = wbase + rank[k];
  __syncthreads();

  // ---- scatter edges into their check's list (unordered) ----
#pragma unroll
  for (int k = 0; k < 4; ++k) {
    int c = slotmap[keys[k]];
    int p = atomicAdd(&cnt[c], 1);
    ce[c * 8 + p] = 4 * t + k;
  }
  // overlap: init odd messages (independent of ce)
  const float xt  = x[t];
  const float th0 = tanhf(0.5f * xt);
  *((float4*)&ods[4 * t]) = make_float4(th0, th0, th0, th0);
  __syncthreads();

  // ---- restore ascending edge order: Batcher 8-sorter, registers only ----
  if (t < Mn) {
    int4 a = *((int4*)&ce[t * 8]);
    int4 b = *((int4*)&ce[t * 8 + 4]);
    int s0 = a.x, s1 = a.y, s2 = a.z, s3 = a.w;
    int s4 = b.x, s5 = b.y, s6 = b.z, s7 = b.w;
#define CEX(p, q) { int lo_ = min(p, q), hi_ = max(p, q); p = lo_; q = hi_; }
    CEX(s0, s1); CEX(s2, s3); CEX(s0, s2); CEX(s1, s3); CEX(s1, s2);  // sort lo
    CEX(s4, s5); CEX(s6, s7); CEX(s4, s6); CEX(s5, s7); CEX(s5, s6);  // sort hi
    CEX(s0, s4); CEX(s2, s6); CEX(s1, s5); CEX(s3, s7);               // merge
    CEX(s2, s4); CEX(s3, s5);
    CEX(s1, s2); CEX(s3, s4); CEX(s5, s6);
#undef CEX
    *((int4*)&ce[t * 8])     = make_int4(s0, s1, s2, s3);
    *((int4*)&ce[t * 8 + 4]) = make_int4(s4, s5, s6, s7);
  }
  __syncthreads();

  // ---- BP iterations (bitwise-identical to reference ordering) ----
  const int c = t >> 1;   // check owned by this thread pair
  const int h = t & 1;    // which half of the 8 outputs this thread emits
  int e[8];
#pragma unroll
  for (int k = 0; k < 8; ++k) e[k] = ce[c * 8 + k];  // loop-invariant
  int eo[4];
#pragma unroll
  for (int kk = 0; kk < 4; ++kk) eo[kk] = h ? e[4 + kk] : e[kk];

  for (int it = 0; it < 5; ++it) {
    // even phase: every thread computes all 8 leave-one-out products
    // (cheap muls, exact same multiply sequence as np.prod), then does
    // atanhf for only its half -> 4 transcendentals/thread, 16 waves busy.
    float f[8];
#pragma unroll
    for (int k = 0; k < 8; ++k) {
      float o = ods[e[k]];
      f[k] = (o == 0.0f) ? 1.0f : o;  // reference's zero->identity subst
    }
    float v[8];
    float p = 1.0f;
#pragma unroll
    for (int k = 0; k < 8; ++k) {
      float vv = p;                   // p = ((1*f0)*f1)*...*f[k-1]  (exact prefix)
#pragma unroll
      for (int j = k + 1; j < 8; ++j) vv *= f[j];  // continue left-to-right
      v[k] = vv;
      p *= f[k];
    }
#pragma unroll
    for (int kk = 0; kk < 4; ++kk) {
      float vv = h ? v[4 + kk] : v[kk];
      if (vv >= 1.0f)       vv =  1.0f - EPSF;
      else if (vv <= -1.0f) vv = -1.0f + EPSF;
      evs[eo[kk]] = 2.0f * atanhf(vv);
    }
    __syncthreads();

    if (it < 4) {
      float4 e4 = *((const float4*)&evs[4 * t]);
      float ev[4] = {e4.x, e4.y, e4.z, e4.w};
      float od[4];
#pragma unroll
      for (int k = 0; k < 4; ++k) {
        float s = 0.0f;
#pragma unroll
        for (int j = 0; j < 4; ++j)
          if (j != k) s += ev[j];  // ascending 3-term sum, same op order
        od[k] = tanhf(0.5f * (xt + s));
      }
      *((float4*)&ods[4 * t]) = make_float4(od[0], od[1], od[2], od[3]);
      __syncthreads();
    }
  }

  // ---- output: sigmoid(x + sum of final evens), same op order ----
  float4 e4 = *((const float4*)&evs[4 * t]);
  float s4  = e4.x + e4.y + e4.z + e4.w;
  float z   = xt + s4;
  out[t]    = 1.0f / (1.0f + expf(-z));
}

// ---------------------------------------------------------------------------
extern "C" void kernel_launch(void* const* d_in, const int* in_sizes, int n_in,
                              void* d_out, int out_size, void* d_ws,
                              size_t ws_size, hipStream_t stream) {
  const float* x    = (const float*)d_in[0];  // [1024]
  const float* w_oe = (const float*)d_in[2];  // w_odd_to_even [4096,4096]
  float* out = (float*)d_out;

  int* f = (int*)d_ws;  // [4096] leftmost peer per edge (every entry written)

  find_first_peer<<<dim3(1024), dim3(256), 0, stream>>>(w_oe, f);
  solve<<<dim3(1), dim3(1024), 0, stream>>>(x, f, out);
}